// Round 8
// baseline (2000.951 us; speedup 1.0000x reference)
//
#include <hip/hip_runtime.h>
#include <hip/hip_bf16.h>

#define N_NODES 50000
#define N_EDGES 600000
#define D_IN 256
#define D 128

#define SCAN_CHUNK 1024
#define N_CHUNKS ((N_NODES + SCAN_CHUNK - 1) / SCAN_CHUNK)  // 49
#define GEMM_BLOCKS ((N_NODES + 31) / 32)                   // 1563
#define EDGE_BLOCKS ((N_EDGES + 255) / 256)                 // 2344
#define OUT_CHUNKS ((N_NODES + 15) / 16)                    // 3125
#define MEGA_GRID 768
#define SPIN_MAX (1 << 15)

typedef unsigned short ushort_t;
typedef __attribute__((ext_vector_type(8))) short bf16x8;
typedef __attribute__((ext_vector_type(16))) float f32x16;

__device__ __forceinline__ float bf2f(ushort_t u) {
  union { unsigned int i; float f; } v;
  v.i = ((unsigned int)u) << 16;
  return v.f;
}
__device__ __forceinline__ ushort_t f2bf(float f) {
  union { float f; unsigned int i; } v;
  v.f = f;
  unsigned int x = v.i;
  unsigned int r = (x + 0x7FFFu + ((x >> 16) & 1u)) >> 16;  // RNE
  return (ushort_t)r;
}
__device__ __forceinline__ float bflo(unsigned int u) {
  union { unsigned int i; float f; } v;
  v.i = u << 16;
  return v.f;
}
__device__ __forceinline__ float bfhi(unsigned int u) {
  union { unsigned int i; float f; } v;
  v.i = u & 0xFFFF0000u;
  return v.f;
}

// ---------------- sync region layout (all 128B-isolated) ----------------
// sync[i*32]            : queue counter for phase i (i=0,1,2)
// sync[96 + i*32]       : barrier i arrive count (i=0..4)
// sync[96 + i*32 + 16]  : barrier i release flag
// Total 512 ints (2KB), zeroed per launch by the memset.

__device__ __forceinline__ void gbar(int* __restrict__ sync, int idx) {
  __syncthreads();
  __threadfence();  // release: make our stores visible across XCDs
  if (threadIdx.x == 0) {
    int* cnt = &sync[96 + idx * 32];
    int* flag = &sync[96 + idx * 32 + 16];
    int prev = __hip_atomic_fetch_add(cnt, 1, __ATOMIC_ACQ_REL,
                                      __HIP_MEMORY_SCOPE_AGENT);
    if (prev == MEGA_GRID - 1) {
      __hip_atomic_store(flag, 1, __ATOMIC_RELEASE, __HIP_MEMORY_SCOPE_AGENT);
    } else {
      int spins = 0;
      while (__hip_atomic_load(flag, __ATOMIC_ACQUIRE,
                               __HIP_MEMORY_SCOPE_AGENT) == 0 &&
             spins < SPIN_MAX) {
        __builtin_amdgcn_s_sleep(16);  // ~1024cy between polls: no LLC hammer
        spins++;
      }
    }
  }
  __syncthreads();
  __threadfence();  // acquire: invalidate caches before reading others' data
}

// ---------------- gather helpers (proven bodies) ----------------
__device__ __forceinline__ void addu4(float acc[8], uint4 u) {
  acc[0] += bflo(u.x);
  acc[1] += bfhi(u.x);
  acc[2] += bflo(u.y);
  acc[3] += bfhi(u.y);
  acc[4] += bflo(u.z);
  acc[5] += bfhi(u.z);
  acc[6] += bflo(u.w);
  acc[7] += bfhi(u.w);
}

__device__ __forceinline__ uint4 ldrow(const char* tbase, int s, int h) {
  return *(const uint4*)(tbase + (((unsigned)s << 8) + ((unsigned)h << 4)));
}

__device__ __forceinline__ void burst8(const char* tbase, int sidx,
                                       int gbase, int qoff, int h, float acc[8]) {
  uint4 u[8];
#pragma unroll
  for (int q = 0; q < 8; q++) {
    int s = __shfl(sidx, gbase + qoff + q);
    u[q] = ldrow(tbase, s, h);
  }
#pragma unroll
  for (int q = 0; q < 8; q++) addu4(acc, u[q]);
}

__device__ __forceinline__ void agg_tail(const char* tbase,
                                         const int* __restrict__ csr,
                                         int e0, int e1, int gbase, int h,
                                         float acc[8]) {
  for (int b2 = e0 + 16; b2 < e1; b2 += 16) {  // rare: deg > 16
    int c2 = e1 - b2;
    int sx = (h < c2) ? csr[b2 + h] : N_NODES;
    burst8(tbase, sx, gbase, 0, h, acc);
    burst8(tbase, sx, gbase, 8, h, acc);
  }
}

// ============================================================================
// MEGA KERNEL v2: plain launch, isolated sync lines, backoff spin, batched
// queue pulls. Phases identical to round-6/7.
// ============================================================================
__global__ __launch_bounds__(256, 4) void k_mega(
    const int* __restrict__ tokens, const int* __restrict__ edge,
    const float* __restrict__ embed,
    const float* __restrict__ wn, const float* __restrict__ bn,
    const float* __restrict__ w1, const float* __restrict__ b1,
    const float* __restrict__ w2, const float* __restrict__ b2,
    float* __restrict__ out_f,
    ushort_t* __restrict__ T1, ushort_t* __restrict__ T2,
    int* __restrict__ epos, float* __restrict__ dinv,
    int* __restrict__ row_start, int* __restrict__ deg,
    int* __restrict__ csr, int* __restrict__ partial,
    ushort_t* __restrict__ WcSw, ushort_t* __restrict__ W2Sw,
    float* __restrict__ bias_ws, int* __restrict__ sync) {
  constexpr int XS = 136;
  __shared__ __align__(16) ushort_t lds_raw[2 * 32 * XS];  // 17408 B
  __shared__ int s_w;
  ushort_t* xh_lds = lds_raw;
  ushort_t* xl_lds = lds_raw + 32 * XS;
  int* ilds = (int*)lds_raw;          // scan scratch (aliased)
  int* plds = ilds + 256;

  const int bid = blockIdx.x;
  const int tid = threadIdx.x;
  const int* srcp = edge;
  const int* dstp = edge + N_EDGES;
  float* bcf = bias_ws;
  float* b1f = bias_ws + 128;
  float* b2f = bias_ws + 256;

  // ================= P0: prep =================
  if (bid < 128) {
    int j = bid;
    int k = tid;
    float acc = 0.f;
#pragma unroll 8
    for (int m = 0; m < 128; m++)
      acc += w1[j * 128 + m] * wn[m * 256 + k];
    ushort_t h = f2bf(acc);
    ushort_t l = f2bf(acc - bf2f(h));
    int wv = j >> 5, fm = j & 31;
    int kh = k >> 7, t = (k >> 4) & 7, fq = (k >> 3) & 1, c = k & 7;
    int lane = fq * 32 + fm;
    int base = ((wv * 2 + kh) * 8 + t) * 2 * 512 + lane * 8 + c;  // KH=2
    WcSw[base] = h;
    WcSw[base + 512] = l;
    if (k == 0) {
      float s = 0.f;
      for (int m = 0; m < 128; m++) s += w1[j * 128 + m] * bn[m];
      bcf[j] = s;
    }
  } else if (bid < 193) {
    int i = (bid - 128) * 256 + tid;
    if (i < 16384) {
      float v = w2[i];
      ushort_t h = f2bf(v);
      ushort_t l = f2bf(v - bf2f(h));
      int j = i >> 7, k = i & 127;
      int wv = j >> 5, fm = j & 31;
      int t = (k >> 4) & 7, fq = (k >> 3) & 1, c = k & 7;
      int lane = fq * 32 + fm;
      int base = (wv * 8 + t) * 2 * 512 + lane * 8 + c;  // KH=1
      W2Sw[base] = h;
      W2Sw[base + 512] = l;
    } else if (i < 16512) {
      b1f[i - 16384] = b1[i - 16384];
    } else if (i < 16640) {
      b2f[i - 16512] = b2[i - 16512];
    }
  } else {
    // deg count AND per-edge slot in one atomic (grid-stride over edges)
    const int estride = (MEGA_GRID - 193) * 256;
    for (int e = (bid - 193) * 256 + tid; e < N_EDGES; e += estride)
      epos[e] = atomicAdd(&deg[dstp[e]], 1);
  }
  gbar(sync, 0);

  // ================= P1: scan partial =================
  if (bid < N_CHUNKS) {
    int base = bid * SCAN_CHUNK + tid * 4;
    int s = 0;
#pragma unroll
    for (int i = 0; i < 4; i++) {
      int idx = base + i;
      if (idx < N_NODES) s += deg[idx];
    }
    ilds[tid] = s;
    __syncthreads();
    for (int off = 128; off > 0; off >>= 1) {
      if (tid < off) ilds[tid] += ilds[tid + off];
      __syncthreads();
    }
    if (tid == 0) partial[bid] = ilds[0];
  }
  gbar(sync, 1);

  // ================= P2: scan final (+dummy rows) =================
  if (bid < N_CHUNKS) {
    if (tid < N_CHUNKS) plds[tid] = partial[tid];
    __syncthreads();
    if (tid == 0) {
      int s = 0;
      for (int i = 0; i < bid; i++) s += plds[i];
      plds[63] = s;
    }
    int base = bid * SCAN_CHUNK + tid * 4;
    int v[4];
    int s = 0;
#pragma unroll
    for (int i = 0; i < 4; i++) {
      int idx = base + i;
      v[i] = (idx < N_NODES) ? deg[idx] : 0;
      s += v[i];
    }
    ilds[tid] = s;
    __syncthreads();
    for (int off = 1; off < 256; off <<= 1) {
      int add = (tid >= off) ? ilds[tid - off] : 0;
      __syncthreads();
      ilds[tid] += add;
      __syncthreads();
    }
    int excl = ilds[tid] - s + plds[63];
#pragma unroll
    for (int i = 0; i < 4; i++) {
      int idx = base + i;
      if (idx < N_NODES) {
        row_start[idx] = excl;
        dinv[idx] = rsqrtf((float)(v[i] + 1));  // +1 self-loop
        excl += v[i];
      }
    }
    if (bid == 0) {
      if (tid == 0) row_start[N_NODES] = N_EDGES;
      unsigned int* z1 = (unsigned int*)&T1[(size_t)N_NODES * D];
      unsigned int* z2 = (unsigned int*)&T2[(size_t)N_NODES * D];
      if (tid < 64) z1[tid] = 0u;
      else if (tid < 128) z2[tid - 64] = 0u;
    }
  }
  gbar(sync, 2);

  // ================= P3: conv1-GEMM || CSR-fill (batched queue) ============
  {
    const int lane = tid & 63;
    const int wv = tid >> 6;
    const int fm = lane & 31;
    const int fq = lane >> 5;
    const int r8 = tid >> 5;
    const int c32 = tid & 31;
    const char* xb = (const char*)embed;
    constexpr int LIMIT = GEMM_BLOCKS + EDGE_BLOCKS;
    constexpr int BATCH = 4;

    for (;;) {
      if (tid == 0) s_w = atomicAdd(&sync[0], BATCH);
      __syncthreads();
      int w0 = s_w;
      __syncthreads();
      if (w0 >= LIMIT) break;
      int wend = min(w0 + BATCH, LIMIT);

      for (int w = w0; w < wend; w++) {
        if (w >= GEMM_BLOCKS) {
          // ---- CSR fill chunk (atomic-free) ----
          int e = (w - GEMM_BLOCKS) * 256 + tid;
          if (e < N_EDGES) {
            int d = dstp[e];
            csr[row_start[d] + epos[e]] = srcp[e];
          }
          continue;
        }

        // ---- GEMM tile w ----
        int node0 = w * 32;
        float4 v0[4], v1[4];
        int rows[4];
#pragma unroll
        for (int i = 0; i < 4; i++) {
          rows[i] = r8 * 4 + i;
          int tk = tokens[min(node0 + rows[i], N_NODES - 1)];
          unsigned off = (unsigned)tk * (D_IN * 4) + (unsigned)c32 * 16;
          v0[i] = *(const float4*)(xb + off);
          v1[i] = *(const float4*)(xb + off + 512);
        }

        f32x16 acc;
#pragma unroll
        for (int r = 0; r < 16; r++) acc[r] = 0.f;

#pragma unroll
        for (int kh = 0; kh < 2; kh++) {
#pragma unroll
          for (int i = 0; i < 4; i++) {
            float4 v = (kh == 0) ? v0[i] : v1[i];
            ushort4 h, l;
            h.x = f2bf(v.x); l.x = f2bf(v.x - bf2f(h.x));
            h.y = f2bf(v.y); l.y = f2bf(v.y - bf2f(h.y));
            h.z = f2bf(v.z); l.z = f2bf(v.z - bf2f(h.z));
            h.w = f2bf(v.w); l.w = f2bf(v.w - bf2f(h.w));
            *(ushort4*)&xh_lds[rows[i] * XS + 4 * c32] = h;
            *(ushort4*)&xl_lds[rows[i] * XS + 4 * c32] = l;
          }
          __syncthreads();

          const ushort_t* wb =
              WcSw + ((size_t)(wv * 2 + kh) * 8) * 2 * 512 + lane * 8;
#pragma unroll
          for (int tc = 0; tc < 2; tc++) {
            bf16x8 wbh[4], wbl[4];
#pragma unroll
            for (int t4 = 0; t4 < 4; t4++) {
              wbh[t4] = *(const bf16x8*)(wb + (size_t)(tc * 4 + t4) * 1024);
              wbl[t4] = *(const bf16x8*)(wb + (size_t)(tc * 4 + t4) * 1024 + 512);
            }
#pragma unroll
            for (int t4 = 0; t4 < 4; t4++) {
              int ko = (tc * 4 + t4) * 16 + fq * 8;
              bf16x8 ah = *(const bf16x8*)&xh_lds[fm * XS + ko];
              bf16x8 al = *(const bf16x8*)&xl_lds[fm * XS + ko];
              acc = __builtin_amdgcn_mfma_f32_32x32x16_bf16(ah, wbh[t4], acc, 0, 0, 0);
              acc = __builtin_amdgcn_mfma_f32_32x32x16_bf16(ah, wbl[t4], acc, 0, 0, 0);
              acc = __builtin_amdgcn_mfma_f32_32x32x16_bf16(al, wbh[t4], acc, 0, 0, 0);
            }
          }
          __syncthreads();  // all reads done before buffer reuse / next tile
        }

        int j = wv * 32 + fm;
        float bv = bcf[j];
#pragma unroll
        for (int r = 0; r < 16; r++) {
          int row = (r & 3) + 8 * (r >> 2) + 4 * fq;
          int node = node0 + row;
          if (node < N_NODES)
            T1[(size_t)node * D + j] = f2bf((acc[r] + bv) * dinv[node]);
        }
      }
    }
  }
  gbar(sync, 3);

  // ================= P4: agg1 + conv2-GEMM (batched queue) =================
  {
    const int lane = tid & 63;
    const int wv = tid >> 6;
    const int fm = lane & 31;
    const int fq = lane >> 5;
    const int g = lane >> 4;
    const int h = lane & 15;
    const int gbase = lane & 48;
    const char* tb = (const char*)T1;
    float4 bA = *(const float4*)&b1f[h * 8];
    float4 bB = *(const float4*)&b1f[h * 8 + 4];
    constexpr int BATCH = 4;

    for (;;) {
      if (tid == 0) s_w = atomicAdd(&sync[32], BATCH);
      __syncthreads();
      int t0 = s_w;
      __syncthreads();
      if (t0 >= GEMM_BLOCKS) break;
      int tend = min(t0 + BATCH, GEMM_BLOCKS);

      for (int t = t0; t < tend; t++) {
        int node0 = t * 32;

        int node0w = node0 + wv * 8;
        int rsv = row_start[min(node0w + min(lane, 8), N_NODES)];
        float dvl = dinv[min(node0w + min(lane, 7), N_NODES - 1)];

        int nodeA = node0w + g;
        int nodeB = node0w + 4 + g;
        int e0A = __shfl(rsv, g), e1A = __shfl(rsv, g + 1);
        int e0B = __shfl(rsv, 4 + g), e1B = __shfl(rsv, 5 + g);
        int cntA = e1A - e0A, cntB = e1B - e0B;
        bool vA = nodeA < N_NODES, vB = nodeB < N_NODES;

        int sidxA = (h < cntA) ? csr[e0A + h] : N_NODES;
        int sidxB = (h < cntB) ? csr[e0B + h] : N_NODES;
        uint4 usA = ldrow(tb, vA ? nodeA : N_NODES, h);
        uint4 usB = ldrow(tb, vB ? nodeB : N_NODES, h);
        float diA = __shfl(dvl, g);
        float diB = __shfl(dvl, 4 + g);

        float accA[8];
#pragma unroll
        for (int q = 0; q < 8; q++) accA[q] = 0.f;
        addu4(accA, usA);
        burst8(tb, sidxA, gbase, 0, h, accA);
        burst8(tb, sidxA, gbase, 8, h, accA);
        agg_tail(tb, csr, e0A, e1A, gbase, h, accA);

        float accB[8];
#pragma unroll
        for (int q = 0; q < 8; q++) accB[q] = 0.f;
        addu4(accB, usB);
        burst8(tb, sidxB, gbase, 0, h, accB);
        burst8(tb, sidxB, gbase, 8, h, accB);
        agg_tail(tb, csr, e0B, e1B, gbase, h, accB);

#pragma unroll
        for (int p = 0; p < 2; p++) {
          float* acc = p ? accB : accA;
          bool vv = p ? vB : vA;
          float di = p ? diB : diA;
          int row = wv * 8 + p * 4 + g;
          bf16x8 ph, pl;
          if (vv) {
            float val[8];
            val[0] = fmaxf(di * acc[0] + bA.x, 0.f);
            val[1] = fmaxf(di * acc[1] + bA.y, 0.f);
            val[2] = fmaxf(di * acc[2] + bA.z, 0.f);
            val[3] = fmaxf(di * acc[3] + bA.w, 0.f);
            val[4] = fmaxf(di * acc[4] + bB.x, 0.f);
            val[5] = fmaxf(di * acc[5] + bB.y, 0.f);
            val[6] = fmaxf(di * acc[6] + bB.z, 0.f);
            val[7] = fmaxf(di * acc[7] + bB.w, 0.f);
#pragma unroll
            for (int q = 0; q < 8; q++) {
              ushort_t hq = f2bf(val[q]);
              ph[q] = (short)hq;
              pl[q] = (short)f2bf(val[q] - bf2f(hq));
            }
          } else {
#pragma unroll
            for (int q = 0; q < 8; q++) { ph[q] = 0; pl[q] = 0; }
          }
          *(bf16x8*)&xh_lds[row * XS + h * 8] = ph;
          *(bf16x8*)&xl_lds[row * XS + h * 8] = pl;
        }
        __syncthreads();

        f32x16 acc;
#pragma unroll
        for (int r = 0; r < 16; r++) acc[r] = 0.f;
        {
          const ushort_t* wb = W2Sw + ((size_t)wv * 8) * 2 * 512 + lane * 8;
#pragma unroll
          for (int tc = 0; tc < 2; tc++) {
            bf16x8 wbh[4], wbl[4];
#pragma unroll
            for (int t4 = 0; t4 < 4; t4++) {
              wbh[t4] = *(const bf16x8*)(wb + (size_t)(tc * 4 + t4) * 1024);
              wbl[t4] = *(const bf16x8*)(wb + (size_t)(tc * 4 + t4) * 1024 + 512);
            }
#pragma unroll
            for (int t4 = 0; t4 < 4; t4++) {
              int ko = (tc * 4 + t4) * 16 + fq * 8;
              bf16x8 ah = *(const bf16x8*)&xh_lds[fm * XS + ko];
              bf16x8 al = *(const bf16x8*)&xl_lds[fm * XS + ko];
              acc = __builtin_amdgcn_mfma_f32_32x32x16_bf16(ah, wbh[t4], acc, 0, 0, 0);
              acc = __builtin_amdgcn_mfma_f32_32x32x16_bf16(ah, wbl[t4], acc, 0, 0, 0);
              acc = __builtin_amdgcn_mfma_f32_32x32x16_bf16(al, wbh[t4], acc, 0, 0, 0);
            }
          }
        }
        int j = wv * 32 + fm;
#pragma unroll
        for (int r = 0; r < 16; r++) {
          int row = (r & 3) + 8 * (r >> 2) + 4 * fq;
          int node = node0 + row;
          if (node < N_NODES)
            T2[(size_t)node * D + j] = f2bf(acc[r] * dinv[node]);
        }
        __syncthreads();  // LDS reuse safe before next tile in batch
      }
    }
  }
  gbar(sync, 4);

  // ================= P5: agg2 + bias -> out (batched queue) ================
  {
    const int lane = tid & 63;
    const int wv = tid >> 6;
    const int g = lane >> 4;
    const int h = lane & 15;
    const int gbase = lane & 48;
    const char* tb = (const char*)T2;
    constexpr int BATCH = 8;

    for (;;) {
      if (tid == 0) s_w = atomicAdd(&sync[64], BATCH);
      __syncthreads();
      int c0 = s_w;
      __syncthreads();
      if (c0 >= OUT_CHUNKS) break;
      int cend = min(c0 + BATCH, OUT_CHUNKS);

      for (int c = c0; c < cend; c++) {
        int nodew = c * 16 + wv * 4;
        int rsv = row_start[min(nodew + min(lane, 4), N_NODES)];
        float dvl = dinv[min(nodew + min(lane, 3), N_NODES - 1)];
        int node = nodew + g;
        int e0 = __shfl(rsv, g), e1 = __shfl(rsv, g + 1);
        int cnt = e1 - e0;
        bool vn = node < N_NODES;

        int sidx = (h < cnt) ? csr[e0 + h] : N_NODES;
        uint4 us = ldrow(tb, vn ? node : N_NODES, h);
        float di = __shfl(dvl, g);

        float acc[8];
#pragma unroll
        for (int q = 0; q < 8; q++) acc[q] = 0.f;
        addu4(acc, us);
        burst8(tb, sidx, gbase, 0, h, acc);
        burst8(tb, sidx, gbase, 8, h, acc);
        agg_tail(tb, csr, e0, e1, gbase, h, acc);

        if (vn) {
          float4 bA = *(const float4*)&b2f[h * 8];
          float4 bB = *(const float4*)&b2f[h * 8 + 4];
          float4 o0, o1;
          o0.x = di * acc[0] + bA.x;
          o0.y = di * acc[1] + bA.y;
          o0.z = di * acc[2] + bA.z;
          o0.w = di * acc[3] + bA.w;
          o1.x = di * acc[4] + bB.x;
          o1.y = di * acc[5] + bB.y;
          o1.z = di * acc[6] + bB.z;
          o1.w = di * acc[7] + bB.w;
          *(float4*)&out_f[(size_t)node * D + h * 8] = o0;
          *(float4*)&out_f[(size_t)node * D + h * 8 + 4] = o1;
        }
      }
    }
  }
}

extern "C" void kernel_launch(void* const* d_in, const int* in_sizes, int n_in,
                              void* d_out, int out_size, void* d_ws, size_t ws_size,
                              hipStream_t stream) {
  const int* tokens = (const int*)d_in[0];
  const int* edge = (const int*)d_in[1];  // [2][E]
  const float* embed = (const float*)d_in[2];
  const float* Wn = (const float*)d_in[3];
  const float* bn = (const float*)d_in[4];
  const float* w1 = (const float*)d_in[5];
  const float* b1 = (const float*)d_in[6];
  const float* w2 = (const float*)d_in[7];
  const float* b2 = (const float*)d_in[8];
  float* out = (float*)d_out;  // fp32 output

  char* ws = (char*)d_ws;
  // T1/T2 have one extra ZERO row at index N_NODES (gather padding target)
  ushort_t* T1 = (ushort_t*)ws;                    // 12,800,256 B
  ushort_t* T2 = (ushort_t*)(ws + 12800256);       // 12,800,256 B
  int* epos = (int*)(ws + 25600512);               // 2,400,000 B (edge slot)
  float* dinv = (float*)(ws + 28000512);           // 200,000 B
  int* row_start = (int*)(ws + 28200512);          // 200,004 B (pad)
  int* deg = (int*)(ws + 28400576);                // 200,000 B
  int* sync = (int*)(ws + 28600576);               // 2,048 B (isolated sync)
  int* csr = (int*)(ws + 28602624);                // 2,400,000 B
  int* partial = (int*)(ws + 31002624);            // 196 B (pad to 512)
  ushort_t* WcSw = (ushort_t*)(ws + 31003136);     // 131,072 B (swizzled hi/lo)
  ushort_t* W2Sw = (ushort_t*)(ws + 31134208);     // 65,536 B (swizzled hi/lo)
  float* bias_ws = (float*)(ws + 31199744);        // bc | b1 | b2 (1,536 B)

  // zero deg + sync region in one contiguous memset (202,048 B)
  hipMemsetAsync(deg, 0, 202048, stream);

  k_mega<<<MEGA_GRID, 256, 0, stream>>>(
      tokens, edge, embed, Wn, bn, w1, b1, w2, b2, out,
      T1, T2, epos, dinv, row_start, deg, csr, partial, WcSw, W2Sw,
      bias_ws, sync);
}

// Round 9
// 227.950 us; speedup vs baseline: 8.7780x; 8.7780x over previous
//
#include <hip/hip_runtime.h>
#include <hip/hip_bf16.h>

#define N_NODES 50000
#define N_EDGES 600000
#define D_IN 256
#define D 128

#define GEMM_BLOCKS ((N_NODES + 31) / 32)    // 1563
#define EDGE_BLOCKS ((N_EDGES + 255) / 256)  // 2344
#define OUT_CHUNKS (N_NODES / 16)            // 3125 (50000 = 16*3125 exactly)
#define BCAP 32                              // bucket capacity per node
#define OVF_CAP 2048                         // overflow entries (P(use)~1e-7)

typedef unsigned short ushort_t;
typedef __attribute__((ext_vector_type(8))) short bf16x8;
typedef __attribute__((ext_vector_type(16))) float f32x16;

__device__ __forceinline__ float bf2f(ushort_t u) {
  union { unsigned int i; float f; } v;
  v.i = ((unsigned int)u) << 16;
  return v.f;
}
__device__ __forceinline__ ushort_t f2bf(float f) {
  union { float f; unsigned int i; } v;
  v.f = f;
  unsigned int x = v.i;
  unsigned int r = (x + 0x7FFFu + ((x >> 16) & 1u)) >> 16;  // RNE
  return (ushort_t)r;
}
__device__ __forceinline__ float bflo(unsigned int u) {
  union { unsigned int i; float f; } v;
  v.i = u << 16;
  return v.f;
}
__device__ __forceinline__ float bfhi(unsigned int u) {
  union { unsigned int i; float f; } v;
  v.i = u & 0xFFFF0000u;
  return v.f;
}

// Swizzled-W addressing: element (j,k) of [128,KDIM] W, hi/lo split:
//   wv=j>>5, fm=j&31, kh=k>>7, t=(k>>4)&7, fq=(k>>3)&1, c=k&7, lane=fq*32+fm
//   addr = (((wv*(KDIM/128)+kh)*8 + t)*2 + hl)*512 + lane*8 + c   [ushorts]

// ---------------- prep + DIRECT bucket fill ----------------
// The deg atomic's return value IS the CSR slot -> write bucket immediately
// (dst/src already in registers). Eliminates the scan kernels and the
// separate fill pass entirely. Overflow (deg>BCAP, P~1e-7) goes to a tiny
// exact list.
__global__ __launch_bounds__(256) void k_prep_fill(
    const float* __restrict__ wn, const float* __restrict__ w1,
    const float* __restrict__ bn, const float* __restrict__ w2,
    const float* __restrict__ b1, const float* __restrict__ b2,
    const int* __restrict__ src, const int* __restrict__ dst,
    ushort_t* __restrict__ WcSw, ushort_t* __restrict__ W2Sw,
    float* __restrict__ bias_ws, int* __restrict__ deg,
    int* __restrict__ bucket, int* __restrict__ ovfc, int* __restrict__ ovf,
    ushort_t* __restrict__ T1z, ushort_t* __restrict__ T2z) {
  int bid = blockIdx.x;
  int tid = threadIdx.x;
  float* bcf = bias_ws;
  float* b1f = bias_ws + 128;
  float* b2f = bias_ws + 256;
  if (bid < 128) {
    int j = bid;
    int k = tid;
    float acc = 0.f;
#pragma unroll 8
    for (int m = 0; m < 128; m++)
      acc += w1[j * 128 + m] * wn[m * 256 + k];
    ushort_t h = f2bf(acc);
    ushort_t l = f2bf(acc - bf2f(h));
    int wv = j >> 5, fm = j & 31;
    int kh = k >> 7, t = (k >> 4) & 7, fq = (k >> 3) & 1, c = k & 7;
    int lane = fq * 32 + fm;
    int base = ((wv * 2 + kh) * 8 + t) * 2 * 512 + lane * 8 + c;  // KH=2
    WcSw[base] = h;
    WcSw[base + 512] = l;
    if (k == 0) {
      float s = 0.f;
      for (int m = 0; m < 128; m++) s += w1[j * 128 + m] * bn[m];
      bcf[j] = s;
    }
  } else if (bid < 193) {
    int i = (bid - 128) * 256 + tid;
    if (i < 16384) {
      float v = w2[i];
      ushort_t h = f2bf(v);
      ushort_t l = f2bf(v - bf2f(h));
      int j = i >> 7, k = i & 127;
      int wv = j >> 5, fm = j & 31;
      int t = (k >> 4) & 7, fq = (k >> 3) & 1, c = k & 7;
      int lane = fq * 32 + fm;
      int base = (wv * 8 + t) * 2 * 512 + lane * 8 + c;  // KH=1
      W2Sw[base] = h;
      W2Sw[base + 512] = l;
    } else if (i < 16512) {
      b1f[i - 16384] = b1[i - 16384];
    } else if (i < 16640) {
      b2f[i - 16512] = b2[i - 16512];
    }
  } else if (bid == 193) {
    // zero the shared dummy row T[N_NODES] (gather padding target)
    unsigned int* z1 = (unsigned int*)&T1z[(size_t)N_NODES * D];
    unsigned int* z2 = (unsigned int*)&T2z[(size_t)N_NODES * D];
    if (tid < 64) z1[tid] = 0u;
    else if (tid < 128) z2[tid - 64] = 0u;
  } else {
    int e = (bid - 194) * 256 + tid;
    if (e < N_EDGES) {
      int d = dst[e];
      int s = src[e];
      int pos = atomicAdd(&deg[d], 1);
      if (pos < BCAP) {
        bucket[d * BCAP + pos] = s;
      } else {
        int oi = atomicAdd(ovfc, 1);
        if (oi < OVF_CAP) {
          ovf[2 * oi] = d;
          ovf[2 * oi + 1] = s;
        }
      }
    }
  }
}

// ---------------- conv1-GEMM ----------------
// K-split staging: one 17.4KB LDS buffer reused for the two K=128 halves.
__global__ __launch_bounds__(256) void k_gemm(
    const float* __restrict__ Xv, const int* __restrict__ tokens,
    const ushort_t* __restrict__ Wsw, const float* __restrict__ bias,
    const int* __restrict__ deg, ushort_t* __restrict__ OutT) {
  constexpr int XS = 136;
  __shared__ __align__(16) ushort_t xh_lds[32 * XS];
  __shared__ __align__(16) ushort_t xl_lds[32 * XS];

  int tid = threadIdx.x;
  int lane = tid & 63;
  int wv = tid >> 6;
  int node0 = blockIdx.x * 32;
  int fm = lane & 31;
  int fq = lane >> 5;
  int r8 = tid >> 5;   // 0..7
  int c32 = tid & 31;  // 0..31

  // load full rows (both K-halves) up-front: 8 independent float4 loads
  const char* xb = (const char*)Xv;
  float4 v0[4], v1[4];
  int rows[4];
#pragma unroll
  for (int i = 0; i < 4; i++) {
    rows[i] = r8 * 4 + i;
    int tk = tokens[min(node0 + rows[i], N_NODES - 1)];
    unsigned off = (unsigned)tk * (D_IN * 4) + (unsigned)c32 * 16;
    v0[i] = *(const float4*)(xb + off);
    v1[i] = *(const float4*)(xb + off + 512);
  }

  f32x16 acc;
#pragma unroll
  for (int r = 0; r < 16; r++) acc[r] = 0.f;

#pragma unroll
  for (int kh = 0; kh < 2; kh++) {
#pragma unroll
    for (int i = 0; i < 4; i++) {
      float4 v = (kh == 0) ? v0[i] : v1[i];
      ushort4 h, l;
      h.x = f2bf(v.x); l.x = f2bf(v.x - bf2f(h.x));
      h.y = f2bf(v.y); l.y = f2bf(v.y - bf2f(h.y));
      h.z = f2bf(v.z); l.z = f2bf(v.z - bf2f(h.z));
      h.w = f2bf(v.w); l.w = f2bf(v.w - bf2f(h.w));
      *(ushort4*)&xh_lds[rows[i] * XS + 4 * c32] = h;
      *(ushort4*)&xl_lds[rows[i] * XS + 4 * c32] = l;
    }
    __syncthreads();

    const ushort_t* wb = Wsw + ((size_t)(wv * 2 + kh) * 8) * 2 * 512 + lane * 8;
#pragma unroll
    for (int tc = 0; tc < 2; tc++) {
      bf16x8 wbh[4], wbl[4];
#pragma unroll
      for (int t4 = 0; t4 < 4; t4++) {
        wbh[t4] = *(const bf16x8*)(wb + (size_t)(tc * 4 + t4) * 1024);
        wbl[t4] = *(const bf16x8*)(wb + (size_t)(tc * 4 + t4) * 1024 + 512);
      }
#pragma unroll
      for (int t4 = 0; t4 < 4; t4++) {
        int ko = (tc * 4 + t4) * 16 + fq * 8;
        bf16x8 ah = *(const bf16x8*)&xh_lds[fm * XS + ko];
        bf16x8 al = *(const bf16x8*)&xl_lds[fm * XS + ko];
        acc = __builtin_amdgcn_mfma_f32_32x32x16_bf16(ah, wbh[t4], acc, 0, 0, 0);
        acc = __builtin_amdgcn_mfma_f32_32x32x16_bf16(ah, wbl[t4], acc, 0, 0, 0);
        acc = __builtin_amdgcn_mfma_f32_32x32x16_bf16(al, wbh[t4], acc, 0, 0, 0);
      }
    }
    if (kh == 0) __syncthreads();  // all reads done before buffer reuse
  }

  int j = wv * 32 + fm;
  float bv = bias[j];
#pragma unroll
  for (int r = 0; r < 16; r++) {
    int row = (r & 3) + 8 * (r >> 2) + 4 * fq;
    int node = node0 + row;
    if (node < N_NODES) {
      float di = rsqrtf((float)(deg[node] + 1));  // +1 self-loop
      OutT[(size_t)node * D + j] = f2bf((acc[r] + bv) * di);
    }
  }
}

// ---------------- bucket gather (branch-free, register-dieted) ----------------
// 16 lanes = 1 node; lane h owns dims h*8..h*8+7 (one uint4).
// Bucket row is node*BCAP contiguous; short rows padded with the zeroed dummy
// row at index N_NODES. Overflow list scanned only when deg > BCAP (P~1e-7).
__device__ __forceinline__ void addu4(float acc[8], uint4 u) {
  acc[0] += bflo(u.x);
  acc[1] += bfhi(u.x);
  acc[2] += bflo(u.y);
  acc[3] += bfhi(u.y);
  acc[4] += bflo(u.z);
  acc[5] += bfhi(u.z);
  acc[6] += bflo(u.w);
  acc[7] += bfhi(u.w);
}

__device__ __forceinline__ uint4 ldrow(const char* tbase, int s, int h) {
  return *(const uint4*)(tbase + (((unsigned)s << 8) + ((unsigned)h << 4)));
}

__device__ __forceinline__ void burst8(const char* tbase, int sidx,
                                       int gbase, int qoff, int h, float acc[8]) {
  uint4 u[8];
#pragma unroll
  for (int q = 0; q < 8; q++) {
    int s = __shfl(sidx, gbase + qoff + q);
    u[q] = ldrow(tbase, s, h);
  }
#pragma unroll
  for (int q = 0; q < 8; q++) addu4(acc, u[q]);
}

// Full per-node gather: self row + bucket + (rare) tail + (ultra-rare) ovf.
__device__ __forceinline__ void gather_node(
    const char* tbase, const int* __restrict__ bucket,
    const int* __restrict__ ovf, int novf,
    int node, int degv, bool valid, int gbase, int h, float acc[8]) {
  int cnt = valid ? min(degv, BCAP) : 0;
  addu4(acc, ldrow(tbase, valid ? node : N_NODES, h));  // self (prescaled)
  int sidx = (h < cnt) ? bucket[node * BCAP + h] : N_NODES;
  burst8(tbase, sidx, gbase, 0, h, acc);
  burst8(tbase, sidx, gbase, 8, h, acc);
  for (int b2 = 16; b2 < cnt; b2 += 16) {  // deg in (16,32]: one more batch
    int sx = (b2 + h < cnt) ? bucket[node * BCAP + b2 + h] : N_NODES;
    burst8(tbase, sx, gbase, 0, h, acc);
    burst8(tbase, sx, gbase, 8, h, acc);
  }
  if (valid && degv > BCAP) {  // exact overflow handling
    for (int i = 0; i < novf; i++) {
      if (ovf[2 * i] == node) addu4(acc, ldrow(tbase, ovf[2 * i + 1], h));
    }
  }
}

// ---------------- FUSED aggregate1 + conv2-GEMM ----------------
__global__ __launch_bounds__(256) void k_agg_gemm(
    const ushort_t* __restrict__ t1, const int* __restrict__ deg,
    const int* __restrict__ bucket, const int* __restrict__ ovfc,
    const int* __restrict__ ovf, const float* __restrict__ b1f,
    const ushort_t* __restrict__ Wsw, ushort_t* __restrict__ OutT2) {
  constexpr int XS = 136;
  __shared__ __align__(16) ushort_t xh_lds[32 * XS];
  __shared__ __align__(16) ushort_t xl_lds[32 * XS];

  int tid = threadIdx.x;
  int lane = tid & 63;
  int wv = tid >> 6;
  int node0 = blockIdx.x * 32;
  int fm = lane & 31;
  int fq = lane >> 5;
  int g = lane >> 4;   // group 0..3
  int h = lane & 15;   // dim-chunk 0..15
  int gbase = lane & 48;

  const char* tb = (const char*)t1;
  float4 bA = *(const float4*)&b1f[h * 8];
  float4 bB = *(const float4*)&b1f[h * 8 + 4];
  int novf = *ovfc;

  // hoisted per-wave deg loads (8 nodes)
  int node0w = node0 + wv * 8;
  int dgl = deg[min(node0w + min(lane, 7), N_NODES - 1)];

  int nodeA = node0w + g;      // pass-0 node (wave rows 0..3)
  int nodeB = node0w + 4 + g;  // pass-1 node (wave rows 4..7)
  int degA = __shfl(dgl, g);
  int degB = __shfl(dgl, 4 + g);
  bool vA = nodeA < N_NODES, vB = nodeB < N_NODES;
  float diA = rsqrtf((float)(degA + 1));
  float diB = rsqrtf((float)(degB + 1));

  float accA[8];
#pragma unroll
  for (int q = 0; q < 8; q++) accA[q] = 0.f;
  gather_node(tb, bucket, ovf, novf, nodeA, degA, vA, gbase, h, accA);

  float accB[8];
#pragma unroll
  for (int q = 0; q < 8; q++) accB[q] = 0.f;
  gather_node(tb, bucket, ovf, novf, nodeB, degB, vB, gbase, h, accB);

  // ---- epilogues -> LDS ----
#pragma unroll
  for (int p = 0; p < 2; p++) {
    float* acc = p ? accB : accA;
    bool vv = p ? vB : vA;
    float di = p ? diB : diA;
    int row = wv * 8 + p * 4 + g;
    bf16x8 ph, pl;
    if (vv) {
      float val[8];
      val[0] = fmaxf(di * acc[0] + bA.x, 0.f);
      val[1] = fmaxf(di * acc[1] + bA.y, 0.f);
      val[2] = fmaxf(di * acc[2] + bA.z, 0.f);
      val[3] = fmaxf(di * acc[3] + bA.w, 0.f);
      val[4] = fmaxf(di * acc[4] + bB.x, 0.f);
      val[5] = fmaxf(di * acc[5] + bB.y, 0.f);
      val[6] = fmaxf(di * acc[6] + bB.z, 0.f);
      val[7] = fmaxf(di * acc[7] + bB.w, 0.f);
#pragma unroll
      for (int q = 0; q < 8; q++) {
        ushort_t hq = f2bf(val[q]);
        ph[q] = (short)hq;
        pl[q] = (short)f2bf(val[q] - bf2f(hq));
      }
    } else {
#pragma unroll
      for (int q = 0; q < 8; q++) { ph[q] = 0; pl[q] = 0; }
    }
    *(bf16x8*)&xh_lds[row * XS + h * 8] = ph;
    *(bf16x8*)&xl_lds[row * XS + h * 8] = pl;
  }
  __syncthreads();

  f32x16 acc;
#pragma unroll
  for (int r = 0; r < 16; r++) acc[r] = 0.f;
  {
    const ushort_t* wb = Wsw + ((size_t)wv * 8) * 2 * 512 + lane * 8;
#pragma unroll
    for (int tc = 0; tc < 2; tc++) {
      bf16x8 wbh[4], wbl[4];
#pragma unroll
      for (int t4 = 0; t4 < 4; t4++) {
        wbh[t4] = *(const bf16x8*)(wb + (size_t)(tc * 4 + t4) * 1024);
        wbl[t4] = *(const bf16x8*)(wb + (size_t)(tc * 4 + t4) * 1024 + 512);
      }
#pragma unroll
      for (int t4 = 0; t4 < 4; t4++) {
        int ko = (tc * 4 + t4) * 16 + fq * 8;
        bf16x8 ah = *(const bf16x8*)&xh_lds[fm * XS + ko];
        bf16x8 al = *(const bf16x8*)&xl_lds[fm * XS + ko];
        acc = __builtin_amdgcn_mfma_f32_32x32x16_bf16(ah, wbh[t4], acc, 0, 0, 0);
        acc = __builtin_amdgcn_mfma_f32_32x32x16_bf16(ah, wbl[t4], acc, 0, 0, 0);
        acc = __builtin_amdgcn_mfma_f32_32x32x16_bf16(al, wbh[t4], acc, 0, 0, 0);
      }
    }
  }
  int j = wv * 32 + fm;
#pragma unroll
  for (int r = 0; r < 16; r++) {
    int row = (r & 3) + 8 * (r >> 2) + 4 * fq;
    int node = node0 + row;
    if (node < N_NODES) {
      float di = rsqrtf((float)(deg[node] + 1));
      OutT2[(size_t)node * D + j] = f2bf(acc[r] * di);
    }
  }
}

// ---------------- final aggregation -> fp32 out ----------------
// 4 nodes per wave, 16 per block (50000 = 16*3125 exactly).
__global__ __launch_bounds__(256) void k_agg_out(
    const ushort_t* __restrict__ t, const int* __restrict__ deg,
    const int* __restrict__ bucket, const int* __restrict__ ovfc,
    const int* __restrict__ ovf, const float* __restrict__ bias,
    float* __restrict__ out_f) {
  int wv = threadIdx.x >> 6;
  int lane = threadIdx.x & 63;
  int g = lane >> 4;
  int h = lane & 15;
  int gbase = lane & 48;
  int nodew = blockIdx.x * 16 + wv * 4;
  int dgl = deg[min(nodew + min(lane, 3), N_NODES - 1)];
  int node = nodew + g;
  int degn = __shfl(dgl, g);
  bool vn = node < N_NODES;
  float di = rsqrtf((float)(degn + 1));
  int novf = *ovfc;

  const char* tb = (const char*)t;
  float acc[8];
#pragma unroll
  for (int q = 0; q < 8; q++) acc[q] = 0.f;
  gather_node(tb, bucket, ovf, novf, node, degn, vn, gbase, h, acc);

  if (!vn) return;
  float4 bA = *(const float4*)&bias[h * 8];
  float4 bB = *(const float4*)&bias[h * 8 + 4];
  float4 o0, o1;
  o0.x = di * acc[0] + bA.x;
  o0.y = di * acc[1] + bA.y;
  o0.z = di * acc[2] + bA.z;
  o0.w = di * acc[3] + bA.w;
  o1.x = di * acc[4] + bB.x;
  o1.y = di * acc[5] + bB.y;
  o1.z = di * acc[6] + bB.z;
  o1.w = di * acc[7] + bB.w;
  *(float4*)&out_f[(size_t)node * D + h * 8] = o0;
  *(float4*)&out_f[(size_t)node * D + h * 8 + 4] = o1;
}

extern "C" void kernel_launch(void* const* d_in, const int* in_sizes, int n_in,
                              void* d_out, int out_size, void* d_ws, size_t ws_size,
                              hipStream_t stream) {
  const int* tokens = (const int*)d_in[0];
  const int* edge = (const int*)d_in[1];  // [2][E]
  const float* embed = (const float*)d_in[2];
  const float* Wn = (const float*)d_in[3];
  const float* bn = (const float*)d_in[4];
  const float* w1 = (const float*)d_in[5];
  const float* b1 = (const float*)d_in[6];
  const float* w2 = (const float*)d_in[7];
  const float* b2 = (const float*)d_in[8];
  float* out = (float*)d_out;  // fp32 output

  const int* src = edge;
  const int* dst = edge + N_EDGES;

  char* ws = (char*)d_ws;
  // T1/T2 have one extra ZERO row at index N_NODES (gather padding target)
  ushort_t* T1 = (ushort_t*)ws;                  // 12,800,256 B
  ushort_t* T2 = (ushort_t*)(ws + 12800256);     // 12,800,256 B
  int* bucket = (int*)(ws + 25600512);           // 6,400,000 B (50K x 32)
  int* deg = (int*)(ws + 32000512);              // 200,000 B
  int* ovfc = (int*)(ws + 32200512);             // 128 B (isolated counter)
  int* ovf = (int*)(ws + 32200640);              // 16,384 B (2048 pairs)
  ushort_t* WcSw = (ushort_t*)(ws + 32217088);   // 131,072 B (swizzled hi/lo)
  ushort_t* W2Sw = (ushort_t*)(ws + 32348160);   // 65,536 B (swizzled hi/lo)
  float* bias_ws = (float*)(ws + 32413696);      // bc | b1 | b2 (1,536 B)
  float* bcf = bias_ws;
  float* b1f = bias_ws + 128;
  float* b2f = bias_ws + 256;

  // zero deg + overflow counter (one contiguous 200,128 B memset)
  hipMemsetAsync(deg, 0, 200128, stream);

  // --- prep: W-fold + copies + DIRECT deg/bucket fill (no scan, no epos) ---
  k_prep_fill<<<194 + EDGE_BLOCKS, 256, 0, stream>>>(
      Wn, w1, bn, w2, b1, b2, src, dst, WcSw, W2Sw, bias_ws, deg,
      bucket, ovfc, ovf, T1, T2);

  // --- conv1: T1 = (gather(e)@Wc^T + bc)*dinv ---
  k_gemm<<<GEMM_BLOCKS, 256, 0, stream>>>(
      embed, tokens, WcSw, bcf, deg, T1);

  // --- fused: x1 = relu(agg(T1)+b1); T2 = (x1 @ w2^T)*dinv ---
  k_agg_gemm<<<GEMM_BLOCKS, 256, 0, stream>>>(
      T1, deg, bucket, ovfc, ovf, b1f, W2Sw, T2);

  // --- final aggregate + b2 -> out (fp32) ---
  k_agg_out<<<OUT_CHUNKS, 256, 0, stream>>>(
      T2, deg, bucket, ovfc, ovf, b2f, out);
}

// Round 10
// 214.604 us; speedup vs baseline: 9.3239x; 1.0622x over previous
//
#include <hip/hip_runtime.h>
#include <hip/hip_bf16.h>

#define N_NODES 50000
#define N_EDGES 600000
#define D_IN 256
#define D 128

#define GEMM_BLOCKS ((N_NODES + 31) / 32)    // 1563
#define EDGE_BLOCKS ((N_EDGES + 255) / 256)  // 2344
#define MIX_BLOCKS 3910                      // 782 groups x 5 (2 gemm + 3 fill)
#define OUT_CHUNKS (N_NODES / 16)            // 3125
#define BCAP 32                              // bucket capacity per node
#define OVF_CAP 2048                         // overflow entries (P(use)~1e-7)

typedef unsigned short ushort_t;
typedef __attribute__((ext_vector_type(8))) short bf16x8;
typedef __attribute__((ext_vector_type(16))) float f32x16;

__device__ __forceinline__ float bf2f(ushort_t u) {
  union { unsigned int i; float f; } v;
  v.i = ((unsigned int)u) << 16;
  return v.f;
}
__device__ __forceinline__ ushort_t f2bf(float f) {
  union { float f; unsigned int i; } v;
  v.f = f;
  unsigned int x = v.i;
  unsigned int r = (x + 0x7FFFu + ((x >> 16) & 1u)) >> 16;  // RNE
  return (ushort_t)r;
}
__device__ __forceinline__ float bflo(unsigned int u) {
  union { unsigned int i; float f; } v;
  v.i = u << 16;
  return v.f;
}
__device__ __forceinline__ float bfhi(unsigned int u) {
  union { unsigned int i; float f; } v;
  v.i = u & 0xFFFF0000u;
  return v.f;
}

// Swizzled-W addressing: element (j,k) of [128,KDIM] W, hi/lo split:
//   wv=j>>5, fm=j&31, kh=k>>7, t=(k>>4)&7, fq=(k>>3)&1, c=k&7, lane=fq*32+fm
//   addr = (((wv*(KDIM/128)+kh)*8 + t)*2 + hl)*512 + lane*8 + c   [ushorts]

// ---------------- k1: weight prep only (no edge work) ----------------
__global__ __launch_bounds__(256) void k_wprep(
    const float* __restrict__ wn, const float* __restrict__ w1,
    const float* __restrict__ bn, const float* __restrict__ w2,
    const float* __restrict__ b1, const float* __restrict__ b2,
    ushort_t* __restrict__ WcSw, ushort_t* __restrict__ W2Sw,
    float* __restrict__ bias_ws,
    ushort_t* __restrict__ T1z, ushort_t* __restrict__ T2z) {
  int bid = blockIdx.x;
  int tid = threadIdx.x;
  float* bcf = bias_ws;
  float* b1f = bias_ws + 128;
  float* b2f = bias_ws + 256;
  if (bid < 128) {
    int j = bid;
    int k = tid;
    float acc = 0.f;
#pragma unroll 8
    for (int m = 0; m < 128; m++)
      acc += w1[j * 128 + m] * wn[m * 256 + k];
    ushort_t h = f2bf(acc);
    ushort_t l = f2bf(acc - bf2f(h));
    int wv = j >> 5, fm = j & 31;
    int kh = k >> 7, t = (k >> 4) & 7, fq = (k >> 3) & 1, c = k & 7;
    int lane = fq * 32 + fm;
    int base = ((wv * 2 + kh) * 8 + t) * 2 * 512 + lane * 8 + c;  // KH=2
    WcSw[base] = h;
    WcSw[base + 512] = l;
    if (k == 0) {
      float s = 0.f;
      for (int m = 0; m < 128; m++) s += w1[j * 128 + m] * bn[m];
      bcf[j] = s;
    }
  } else if (bid < 193) {
    int i = (bid - 128) * 256 + tid;
    if (i < 16384) {
      float v = w2[i];
      ushort_t h = f2bf(v);
      ushort_t l = f2bf(v - bf2f(h));
      int j = i >> 7, k = i & 127;
      int wv = j >> 5, fm = j & 31;
      int t = (k >> 4) & 7, fq = (k >> 3) & 1, c = k & 7;
      int lane = fq * 32 + fm;
      int base = (wv * 8 + t) * 2 * 512 + lane * 8 + c;  // KH=1
      W2Sw[base] = h;
      W2Sw[base + 512] = l;
    } else if (i < 16512) {
      b1f[i - 16384] = b1[i - 16384];
    } else if (i < 16640) {
      b2f[i - 16512] = b2[i - 16512];
    }
  } else {
    // zero the shared dummy row T[N_NODES] (gather padding target)
    unsigned int* z1 = (unsigned int*)&T1z[(size_t)N_NODES * D];
    unsigned int* z2 = (unsigned int*)&T2z[(size_t)N_NODES * D];
    if (tid < 64) z1[tid] = 0u;
    else if (tid < 128) z2[tid - 64] = 0u;
  }
}

// ---------------- k2: conv1-GEMM (UNSCALED T1) || edge fill ----------------
// T1 is no longer pre-scaled by dinv -> the GEMM has NO dependency on deg,
// so the edge fill (deg atomic + ushort bucket) runs CONCURRENTLY in the
// same dispatch, interleaved 2:3 so both populate all CUs together. The
// fill's atomic latency hides in the GEMM's idle memory slots.
__global__ __launch_bounds__(256) void k_gemm_fill(
    const float* __restrict__ Xv, const int* __restrict__ tokens,
    const ushort_t* __restrict__ Wsw, const float* __restrict__ bias,
    ushort_t* __restrict__ OutT,
    const int* __restrict__ src, const int* __restrict__ dst,
    int* __restrict__ deg, ushort_t* __restrict__ bucket,
    int* __restrict__ ovfc, int* __restrict__ ovf) {
  constexpr int XS = 136;
  __shared__ __align__(16) ushort_t xh_lds[32 * XS];
  __shared__ __align__(16) ushort_t xl_lds[32 * XS];

  int bid = blockIdx.x;
  int tid = threadIdx.x;
  int grp = bid / 5, r = bid % 5;
  if (r >= 2) {
    // ---- fill path: deg atomic gives the slot; ushort bucket row = 64B ----
    int c = grp * 3 + (r - 2);
    if (c >= EDGE_BLOCKS) return;
    int e = c * 256 + tid;
    if (e < N_EDGES) {
      int d = dst[e];
      int s = src[e];
      int pos = atomicAdd(&deg[d], 1);
      if (pos < BCAP) {
        bucket[d * BCAP + pos] = (ushort_t)s;
      } else {
        int oi = atomicAdd(ovfc, 1);
        if (oi < OVF_CAP) {
          ovf[2 * oi] = d;
          ovf[2 * oi + 1] = s;
        }
      }
    }
    return;
  }

  // ---- GEMM path ----
  int t = grp * 2 + r;
  if (t >= GEMM_BLOCKS) return;
  int lane = tid & 63;
  int wv = tid >> 6;
  int node0 = t * 32;
  int fm = lane & 31;
  int fq = lane >> 5;
  int r8 = tid >> 5;   // 0..7
  int c32 = tid & 31;  // 0..31

  const char* xb = (const char*)Xv;
  float4 v0[4], v1[4];
  int rows[4];
#pragma unroll
  for (int i = 0; i < 4; i++) {
    rows[i] = r8 * 4 + i;
    int tk = tokens[min(node0 + rows[i], N_NODES - 1)];
    unsigned off = (unsigned)tk * (D_IN * 4) + (unsigned)c32 * 16;
    v0[i] = *(const float4*)(xb + off);
    v1[i] = *(const float4*)(xb + off + 512);
  }

  f32x16 acc;
#pragma unroll
  for (int q = 0; q < 16; q++) acc[q] = 0.f;

#pragma unroll
  for (int kh = 0; kh < 2; kh++) {
#pragma unroll
    for (int i = 0; i < 4; i++) {
      float4 v = (kh == 0) ? v0[i] : v1[i];
      ushort4 h, l;
      h.x = f2bf(v.x); l.x = f2bf(v.x - bf2f(h.x));
      h.y = f2bf(v.y); l.y = f2bf(v.y - bf2f(h.y));
      h.z = f2bf(v.z); l.z = f2bf(v.z - bf2f(h.z));
      h.w = f2bf(v.w); l.w = f2bf(v.w - bf2f(h.w));
      *(ushort4*)&xh_lds[rows[i] * XS + 4 * c32] = h;
      *(ushort4*)&xl_lds[rows[i] * XS + 4 * c32] = l;
    }
    __syncthreads();

    const ushort_t* wb = Wsw + ((size_t)(wv * 2 + kh) * 8) * 2 * 512 + lane * 8;
#pragma unroll
    for (int tc = 0; tc < 2; tc++) {
      bf16x8 wbh[4], wbl[4];
#pragma unroll
      for (int t4 = 0; t4 < 4; t4++) {
        wbh[t4] = *(const bf16x8*)(wb + (size_t)(tc * 4 + t4) * 1024);
        wbl[t4] = *(const bf16x8*)(wb + (size_t)(tc * 4 + t4) * 1024 + 512);
      }
#pragma unroll
      for (int t4 = 0; t4 < 4; t4++) {
        int ko = (tc * 4 + t4) * 16 + fq * 8;
        bf16x8 ah = *(const bf16x8*)&xh_lds[fm * XS + ko];
        bf16x8 al = *(const bf16x8*)&xl_lds[fm * XS + ko];
        acc = __builtin_amdgcn_mfma_f32_32x32x16_bf16(ah, wbh[t4], acc, 0, 0, 0);
        acc = __builtin_amdgcn_mfma_f32_32x32x16_bf16(ah, wbl[t4], acc, 0, 0, 0);
        acc = __builtin_amdgcn_mfma_f32_32x32x16_bf16(al, wbh[t4], acc, 0, 0, 0);
      }
    }
    if (kh == 0) __syncthreads();  // all reads done before buffer reuse
  }

  int j = wv * 32 + fm;
  float bv = bias[j];
#pragma unroll
  for (int q = 0; q < 16; q++) {
    int row = (q & 3) + 8 * (q >> 2) + 4 * fq;
    int node = node0 + row;
    if (node < N_NODES)
      OutT[(size_t)node * D + j] = f2bf(acc[q] + bv);  // UNSCALED
  }
}

// ---------------- bucket gather with per-row dinv scaling ----------------
// 16 lanes = 1 node; lane h owns dims h*8..h*8+7 (one uint4).
// T rows are UNSCALED; each gathered row is scaled by dinv[s]=rsqrt(deg[s]+1)
// via FMA (same VALU count as the old extract+add). The deg[sidx] load
// issues concurrently with the row bursts (no extra serial round-trip).
__device__ __forceinline__ void fma8(float acc[8], uint4 u, float f) {
  acc[0] = fmaf(bflo(u.x), f, acc[0]);
  acc[1] = fmaf(bfhi(u.x), f, acc[1]);
  acc[2] = fmaf(bflo(u.y), f, acc[2]);
  acc[3] = fmaf(bfhi(u.y), f, acc[3]);
  acc[4] = fmaf(bflo(u.z), f, acc[4]);
  acc[5] = fmaf(bfhi(u.z), f, acc[5]);
  acc[6] = fmaf(bflo(u.w), f, acc[6]);
  acc[7] = fmaf(bfhi(u.w), f, acc[7]);
}

__device__ __forceinline__ uint4 ldrow(const char* tbase, int s, int h) {
  return *(const uint4*)(tbase + (((unsigned)s << 8) + ((unsigned)h << 4)));
}

__device__ __forceinline__ void burst8s(const char* tbase, int sidx, float scl,
                                        int gbase, int qoff, int h, float acc[8]) {
  uint4 u[8];
  float f[8];
#pragma unroll
  for (int q = 0; q < 8; q++) {
    int s = __shfl(sidx, gbase + qoff + q);
    f[q] = __shfl(scl, gbase + qoff + q);
    u[q] = ldrow(tbase, s, h);
  }
#pragma unroll
  for (int q = 0; q < 8; q++) fma8(acc, u[q], f[q]);
}

// Full per-node gather (edges only; self row added by caller with own di).
__device__ __forceinline__ void gather_node(
    const char* tbase, const ushort_t* __restrict__ bucket,
    const int* __restrict__ deg, const int* __restrict__ ovf, int novf,
    int node, int degv, bool valid, int gbase, int h, float acc[8]) {
  int cnt = valid ? min(degv, BCAP) : 0;
  int sidx = (h < cnt) ? (int)bucket[node * BCAP + h] : N_NODES;
  float scl = rsqrtf((float)(deg[sidx] + 1));  // deg[N_NODES]=0 -> 1.0, row=0
  burst8s(tbase, sidx, scl, gbase, 0, h, acc);
  burst8s(tbase, sidx, scl, gbase, 8, h, acc);
  for (int b2 = 16; b2 < cnt; b2 += 16) {  // deg in (16,32]: one more batch
    int sx = (b2 + h < cnt) ? (int)bucket[node * BCAP + b2 + h] : N_NODES;
    float sc = rsqrtf((float)(deg[sx] + 1));
    burst8s(tbase, sx, sc, gbase, 0, h, acc);
    burst8s(tbase, sx, sc, gbase, 8, h, acc);
  }
  if (valid && degv > BCAP) {  // exact overflow handling (P~1e-7)
    for (int i = 0; i < novf; i++) {
      if (ovf[2 * i] == node) {
        int s = ovf[2 * i + 1];
        fma8(acc, ldrow(tbase, s, h), rsqrtf((float)(deg[s] + 1)));
      }
    }
  }
}

// ---------------- FUSED aggregate1 + conv2-GEMM ----------------
__global__ __launch_bounds__(256) void k_agg_gemm(
    const ushort_t* __restrict__ t1, const int* __restrict__ deg,
    const ushort_t* __restrict__ bucket, const int* __restrict__ ovfc,
    const int* __restrict__ ovf, const float* __restrict__ b1f,
    const ushort_t* __restrict__ Wsw, ushort_t* __restrict__ OutT2) {
  constexpr int XS = 136;
  __shared__ __align__(16) ushort_t xh_lds[32 * XS];
  __shared__ __align__(16) ushort_t xl_lds[32 * XS];

  int tid = threadIdx.x;
  int lane = tid & 63;
  int wv = tid >> 6;
  int node0 = blockIdx.x * 32;
  int fm = lane & 31;
  int fq = lane >> 5;
  int g = lane >> 4;   // group 0..3
  int h = lane & 15;   // dim-chunk 0..15
  int gbase = lane & 48;

  const char* tb = (const char*)t1;
  float4 bA = *(const float4*)&b1f[h * 8];
  float4 bB = *(const float4*)&b1f[h * 8 + 4];
  int novf = *ovfc;

  // hoisted per-wave deg loads (8 nodes)
  int node0w = node0 + wv * 8;
  int dgl = deg[min(node0w + min(lane, 7), N_NODES - 1)];

  int nodeA = node0w + g;      // pass-0 node (wave rows 0..3)
  int nodeB = node0w + 4 + g;  // pass-1 node (wave rows 4..7)
  int degA = __shfl(dgl, g);
  int degB = __shfl(dgl, 4 + g);
  bool vA = nodeA < N_NODES, vB = nodeB < N_NODES;
  float diA = rsqrtf((float)(degA + 1));
  float diB = rsqrtf((float)(degB + 1));

  float accA[8];
#pragma unroll
  for (int q = 0; q < 8; q++) accA[q] = 0.f;
  fma8(accA, ldrow(tb, vA ? nodeA : N_NODES, h), diA);  // self * own dinv
  gather_node(tb, bucket, deg, ovf, novf, nodeA, degA, vA, gbase, h, accA);

  float accB[8];
#pragma unroll
  for (int q = 0; q < 8; q++) accB[q] = 0.f;
  fma8(accB, ldrow(tb, vB ? nodeB : N_NODES, h), diB);
  gather_node(tb, bucket, deg, ovf, novf, nodeB, degB, vB, gbase, h, accB);

  // ---- epilogues -> LDS ----
#pragma unroll
  for (int p = 0; p < 2; p++) {
    float* acc = p ? accB : accA;
    bool vv = p ? vB : vA;
    float di = p ? diB : diA;
    int row = wv * 8 + p * 4 + g;
    bf16x8 ph, pl;
    if (vv) {
      float val[8];
      val[0] = fmaxf(di * acc[0] + bA.x, 0.f);
      val[1] = fmaxf(di * acc[1] + bA.y, 0.f);
      val[2] = fmaxf(di * acc[2] + bA.z, 0.f);
      val[3] = fmaxf(di * acc[3] + bA.w, 0.f);
      val[4] = fmaxf(di * acc[4] + bB.x, 0.f);
      val[5] = fmaxf(di * acc[5] + bB.y, 0.f);
      val[6] = fmaxf(di * acc[6] + bB.z, 0.f);
      val[7] = fmaxf(di * acc[7] + bB.w, 0.f);
#pragma unroll
      for (int q = 0; q < 8; q++) {
        ushort_t hq = f2bf(val[q]);
        ph[q] = (short)hq;
        pl[q] = (short)f2bf(val[q] - bf2f(hq));
      }
    } else {
#pragma unroll
      for (int q = 0; q < 8; q++) { ph[q] = 0; pl[q] = 0; }
    }
    *(bf16x8*)&xh_lds[row * XS + h * 8] = ph;
    *(bf16x8*)&xl_lds[row * XS + h * 8] = pl;
  }
  __syncthreads();

  f32x16 acc;
#pragma unroll
  for (int q = 0; q < 16; q++) acc[q] = 0.f;
  {
    const ushort_t* wb = Wsw + ((size_t)wv * 8) * 2 * 512 + lane * 8;
#pragma unroll
    for (int tc = 0; tc < 2; tc++) {
      bf16x8 wbh[4], wbl[4];
#pragma unroll
      for (int t4 = 0; t4 < 4; t4++) {
        wbh[t4] = *(const bf16x8*)(wb + (size_t)(tc * 4 + t4) * 1024);
        wbl[t4] = *(const bf16x8*)(wb + (size_t)(tc * 4 + t4) * 1024 + 512);
      }
#pragma unroll
      for (int t4 = 0; t4 < 4; t4++) {
        int ko = (tc * 4 + t4) * 16 + fq * 8;
        bf16x8 ah = *(const bf16x8*)&xh_lds[fm * XS + ko];
        bf16x8 al = *(const bf16x8*)&xl_lds[fm * XS + ko];
        acc = __builtin_amdgcn_mfma_f32_32x32x16_bf16(ah, wbh[t4], acc, 0, 0, 0);
        acc = __builtin_amdgcn_mfma_f32_32x32x16_bf16(ah, wbl[t4], acc, 0, 0, 0);
        acc = __builtin_amdgcn_mfma_f32_32x32x16_bf16(al, wbh[t4], acc, 0, 0, 0);
      }
    }
  }
  int j = wv * 32 + fm;
#pragma unroll
  for (int q = 0; q < 16; q++) {
    int row = (q & 3) + 8 * (q >> 2) + 4 * fq;
    int node = node0 + row;
    if (node < N_NODES)
      OutT2[(size_t)node * D + j] = f2bf(acc[q]);  // UNSCALED
  }
}

// ---------------- final aggregation -> fp32 out ----------------
__global__ __launch_bounds__(256) void k_agg_out(
    const ushort_t* __restrict__ t, const int* __restrict__ deg,
    const ushort_t* __restrict__ bucket, const int* __restrict__ ovfc,
    const int* __restrict__ ovf, const float* __restrict__ bias,
    float* __restrict__ out_f) {
  int wv = threadIdx.x >> 6;
  int lane = threadIdx.x & 63;
  int g = lane >> 4;
  int h = lane & 15;
  int gbase = lane & 48;
  int nodew = blockIdx.x * 16 + wv * 4;
  int dgl = deg[min(nodew + min(lane, 3), N_NODES - 1)];
  int node = nodew + g;
  int degn = __shfl(dgl, g);
  bool vn = node < N_NODES;
  float di = rsqrtf((float)(degn + 1));
  int novf = *ovfc;

  const char* tb = (const char*)t;
  float acc[8];
#pragma unroll
  for (int q = 0; q < 8; q++) acc[q] = 0.f;
  fma8(acc, ldrow(tb, vn ? node : N_NODES, h), di);  // self * own dinv
  gather_node(tb, bucket, deg, ovf, novf, node, degn, vn, gbase, h, acc);

  if (!vn) return;
  float4 bA = *(const float4*)&bias[h * 8];
  float4 bB = *(const float4*)&bias[h * 8 + 4];
  float4 o0, o1;
  o0.x = di * acc[0] + bA.x;
  o0.y = di * acc[1] + bA.y;
  o0.z = di * acc[2] + bA.z;
  o0.w = di * acc[3] + bA.w;
  o1.x = di * acc[4] + bB.x;
  o1.y = di * acc[5] + bB.y;
  o1.z = di * acc[6] + bB.z;
  o1.w = di * acc[7] + bB.w;
  *(float4*)&out_f[(size_t)node * D + h * 8] = o0;
  *(float4*)&out_f[(size_t)node * D + h * 8 + 4] = o1;
}

extern "C" void kernel_launch(void* const* d_in, const int* in_sizes, int n_in,
                              void* d_out, int out_size, void* d_ws, size_t ws_size,
                              hipStream_t stream) {
  const int* tokens = (const int*)d_in[0];
  const int* edge = (const int*)d_in[1];  // [2][E]
  const float* embed = (const float*)d_in[2];
  const float* Wn = (const float*)d_in[3];
  const float* bn = (const float*)d_in[4];
  const float* w1 = (const float*)d_in[5];
  const float* b1 = (const float*)d_in[6];
  const float* w2 = (const float*)d_in[7];
  const float* b2 = (const float*)d_in[8];
  float* out = (float*)d_out;  // fp32 output

  const int* src = edge;
  const int* dst = edge + N_EDGES;

  char* ws = (char*)d_ws;
  // T1/T2 have one extra ZERO row at index N_NODES (gather padding target)
  ushort_t* T1 = (ushort_t*)ws;                  // 12,800,256 B
  ushort_t* T2 = (ushort_t*)(ws + 12800256);     // 12,800,256 B
  ushort_t* bucket = (ushort_t*)(ws + 25600512); // 3,200,000 B (50K x 32 u16)
  int* deg = (int*)(ws + 28800512);              // 200,064 B (50001 ints, pad)
  int* ovfc = (int*)(ws + 29000576);             // 128 B (isolated counter)
  int* ovf = (int*)(ws + 29000704);              // 16,384 B (2048 pairs)
  ushort_t* WcSw = (ushort_t*)(ws + 29017088);   // 131,072 B (swizzled hi/lo)
  ushort_t* W2Sw = (ushort_t*)(ws + 29148160);   // 65,536 B (swizzled hi/lo)
  float* bias_ws = (float*)(ws + 29213696);      // bc | b1 | b2 (1,536 B)
  float* bcf = bias_ws;
  float* b1f = bias_ws + 128;
  float* b2f = bias_ws + 256;

  // zero deg (incl. deg[N_NODES]=0 for dummy-row scale) + overflow counter
  hipMemsetAsync(deg, 0, 200192, stream);

  // --- k1: weight prep only (small, fast) ---
  k_wprep<<<194, 256, 0, stream>>>(
      Wn, w1, bn, w2, b1, b2, WcSw, W2Sw, bias_ws, T1, T2);

  // --- k2: conv1 T1 = gather(e)@Wc^T + bc (UNSCALED) || edge fill ---
  k_gemm_fill<<<MIX_BLOCKS, 256, 0, stream>>>(
      embed, tokens, WcSw, bcf, T1, src, dst, deg, bucket, ovfc, ovf);

  // --- k3: x1 = relu(dinv*agg_scaled(T1)+b1); T2 = x1@w2^T (UNSCALED) ---
  k_agg_gemm<<<GEMM_BLOCKS, 256, 0, stream>>>(
      T1, deg, bucket, ovfc, ovf, b1f, W2Sw, T2);

  // --- k4: out = dinv*agg_scaled(T2) + b2 (fp32) ---
  k_agg_out<<<OUT_CHUNKS, 256, 0, stream>>>(
      T2, deg, bucket, ovfc, ovf, b2f, out);
}